// Round 5
// baseline (299.424 us; speedup 1.0000x reference)
//
#include <hip/hip_runtime.h>

typedef unsigned short u16;
typedef unsigned int u32;
typedef __attribute__((ext_vector_type(8))) short bf16x8;
typedef __attribute__((ext_vector_type(4))) float f32x4;
typedef __attribute__((ext_vector_type(2))) float f32x2;

#define NND 50000
#define NE 800000
#define NH 8
#define ND 32
#define NTY 5
#define NV (NND * 4)              // virtual nodes: (node, src-quarter)
#define SQSH 14                   // src-quarter = src >> 14

__device__ inline u16 f2bf(float x){
  u32 u = __float_as_uint(x);
  return (u16)((u + 0x7FFFu + ((u >> 16) & 1u)) >> 16);
}

// ---------------- W pre-convert: fc_w fp32 -> bf16 once
__global__ __launch_bounds__(256) void wcvt_k(const float* __restrict__ W,
                                              u16* __restrict__ Wb){
  int i = (blockIdx.x * 256 + threadIdx.x) * 4;
  f32x4 v = __builtin_nontemporal_load((const f32x4*)(W + i));
  ushort4 h = make_ushort4(f2bf(v[0]), f2bf(v[1]), f2bf(v[2]), f2bf(v[3]));
  *(ushort4*)(Wb + i) = h;
}

// ---------------- GEMM: feat[M,256] @ fc_w[256,256]^T -> feat_src bf16, stored
// PAIR-QUARTER-MAJOR: fsrc[q][node][64] (q = col>>6) -> 128B rows so agg's
// gather is one full cache line per edge (request-rate floor; round-3 lesson).
__global__ __launch_bounds__(512, 4) void gemm_k(const float* __restrict__ A,
                                                 const u16* __restrict__ Wb,
                                                 u16* __restrict__ C, int M){
  __shared__ u16 As[128 * 64];  // 16KB: addr(r,ch) u16s = r*64 + ((ch^(r&7))*8)
  __shared__ u16 Ws[256 * 64];  // 32KB: addr(n,ch) u16s = n*64 + ((ch^(n&7))*8)
  const int tid  = threadIdx.x;
  const int m0   = blockIdx.x * 128;
  const int lane = tid & 63, wid = tid >> 6;
  const int wm = (wid >> 2) * 64, wn = (wid & 3) * 64;
  const int ml = lane & 15, quad = lane >> 4;

  f32x4 acc[4][4] = {};

  const int ra = tid >> 2, ca0 = (tid & 3) * 2;
  int rag = m0 + ra; if (rag >= M) rag = M - 1;   // clamp: garbage rows never stored
  const float* aRow = A + (size_t)rag * 256;
  const int rw = tid >> 1, hw = tid & 1;
  const u16* wRow = Wb + (size_t)rw * 256;

  for (int k0 = 0; k0 < 256; k0 += 64){
    #pragma unroll
    for (int q = 0; q < 2; q++){
      int ch = ca0 + q;
      f32x4 v0 = __builtin_nontemporal_load((const f32x4*)(aRow + k0 + ch * 8));
      f32x4 v1 = __builtin_nontemporal_load((const f32x4*)(aRow + k0 + ch * 8 + 4));
      ushort4 h0 = make_ushort4(f2bf(v0[0]), f2bf(v0[1]), f2bf(v0[2]), f2bf(v0[3]));
      ushort4 h1 = make_ushort4(f2bf(v1[0]), f2bf(v1[1]), f2bf(v1[2]), f2bf(v1[3]));
      u16* p = As + ra * 64 + ((ch ^ (ra & 7)) * 8);
      *(ushort4*)p = h0;
      *(ushort4*)(p + 4) = h1;
    }
    #pragma unroll
    for (int q = 0; q < 4; q++){
      int ch = hw * 4 + q;
      uint4 wv = *(const uint4*)(wRow + k0 + ch * 8);
      *(uint4*)(Ws + rw * 64 + ((ch ^ (rw & 7)) * 8)) = wv;
    }
    __syncthreads();
    #pragma unroll
    for (int kk = 0; kk < 64; kk += 32){
      bf16x8 af[4], wf[4];
      const int cA = (kk >> 3) + quad;
      #pragma unroll
      for (int t = 0; t < 4; t++){
        int r = wm + t * 16 + ml;
        af[t] = *(const bf16x8*)(As + r * 64 + ((cA ^ (r & 7)) * 8));
      }
      #pragma unroll
      for (int t = 0; t < 4; t++){
        int n = wn + t * 16 + ml;
        wf[t] = *(const bf16x8*)(Ws + n * 64 + ((cA ^ (n & 7)) * 8));
      }
      #pragma unroll
      for (int i = 0; i < 4; i++)
        #pragma unroll
        for (int j = 0; j < 4; j++)
          acc[i][j] = __builtin_amdgcn_mfma_f32_16x16x32_bf16(af[i], wf[j], acc[i][j], 0, 0, 0);
    }
    __syncthreads();
  }
  const size_t qoff = (size_t)(wn >> 6) * NND * 64;
  #pragma unroll
  for (int i = 0; i < 4; i++){
    #pragma unroll
    for (int rr = 0; rr < 4; rr++){
      int row = m0 + wm + i * 16 + quad * 4 + rr;
      if (row < M){
        u16* crow = C + qoff + (size_t)row * 64;
        #pragma unroll
        for (int j = 0; j < 4; j++)
          __builtin_nontemporal_store(f2bf(acc[i][j][rr]), crow + j * 16 + ml);
      }
    }
  }
}

// ---------------- count: per-(dst, src-quarter) degree only (no epos)
__global__ __launch_bounds__(256) void count_k(const int* __restrict__ dst,
                                               const int* __restrict__ src,
                                               int* __restrict__ deg4){
  int e = blockIdx.x * 256 + threadIdx.x;
  if (e < NE)
    atomicAdd(&deg4[dst[e] * 4 + (src[e] >> SQSH)], 1);
}

// ---------------- scan NV=200k bucket degrees -> local offsets + block sums.
// BONUS: thread's tsum over its 4 consecutive deg4 entries IS the total degree
// of node b*256+tid -> emit degn for the windowed degree sort.
__global__ __launch_bounds__(256) void scan1_k(const int* __restrict__ deg4,
                                               int* __restrict__ offs4,
                                               int* __restrict__ bsum,
                                               int* __restrict__ degn){
  __shared__ int lds[256];
  int b = blockIdx.x, tid = threadIdx.x;
  int base = b * 1024 + tid * 4;
  int d[4]; int tsum = 0;
  #pragma unroll
  for (int j = 0; j < 4; j++){
    int v = (base + j < NV) ? deg4[base + j] : 0;
    d[j] = tsum; tsum += v;
  }
  int node = b * 256 + tid;
  if (node < NND) degn[node] = tsum;
  lds[tid] = tsum; __syncthreads();
  for (int off = 1; off < 256; off <<= 1){
    int v = (tid >= off) ? lds[tid - off] : 0;
    __syncthreads();
    lds[tid] += v;
    __syncthreads();
  }
  int excl = lds[tid] - tsum;
  #pragma unroll
  for (int j = 0; j < 4; j++)
    if (base + j < NV) offs4[base + j] = excl + d[j];
  if (tid == 255) bsum[b] = lds[tid];
}

// 256-wide scan over up to 256 block sums (NV/1024 = 196 blocks)
__global__ __launch_bounds__(256) void scan2_k(const int* __restrict__ bsum,
                                               int* __restrict__ bbase, int nb){
  __shared__ int l[256];
  int tid = threadIdx.x;
  int v = (tid < nb) ? bsum[tid] : 0;
  l[tid] = v; __syncthreads();
  for (int off = 1; off < 256; off <<= 1){
    int u = (tid >= off) ? l[tid - off] : 0;
    __syncthreads();
    l[tid] += u;
    __syncthreads();
  }
  bbase[tid] = l[tid] - v;
}

// ---------------- prep: (a) cursor[v] = absolute start offset (consumed by
// scatter's atomicAdd -> becomes END offset, which agg uses); (b) WINDOWED
// DEGREE SORT: counting-sort the 1024 nodes of this window by total degree ->
// nperm. agg waves then carry 8 near-equal-degree nodes (divergence ~0) while
// csr reads stay within a 64KB window (locality preserved vs a global sort).
__global__ __launch_bounds__(256) void prep_k(const int* __restrict__ degn,
                                              const int* __restrict__ offs4,
                                              const int* __restrict__ bbase4,
                                              int* __restrict__ cursor,
                                              int* __restrict__ nperm){
  __shared__ int hist[64], hcur[64];
  int b = blockIdx.x, tid = threadIdx.x;
  // cursor init: 4096 v-entries per block
  int vbase = b * 4096;
  #pragma unroll
  for (int j = 0; j < 16; j++){
    int v = vbase + tid + j * 256;
    if (v < NV) cursor[v] = offs4[v] + bbase4[v >> 10];
  }
  if (tid < 64) hist[tid] = 0;
  __syncthreads();
  int n0 = b * 1024;
  int myn[4], mybin[4];
  #pragma unroll
  for (int j = 0; j < 4; j++){
    int idx = tid * 4 + j;
    int n = n0 + idx;
    myn[j] = -1;
    if (n < NND){
      int dg = degn[n];
      int bin = dg > 63 ? 63 : dg;
      myn[j] = n; mybin[j] = bin;
      atomicAdd(&hist[bin], 1);
    }
  }
  __syncthreads();
  if (tid == 0){
    int acc = 0;
    for (int i = 0; i < 64; i++){ int t = hist[i]; hcur[i] = acc; acc += t; }
  }
  __syncthreads();
  #pragma unroll
  for (int j = 0; j < 4; j++){
    if (myn[j] >= 0){
      int pos = n0 + atomicAdd(&hcur[mybin[j]], 1);
      nperm[pos] = myn[j];
    }
  }
}

// ---------------- scatter edges into src-bucketed CSR via cursor atomics
// csr entry = (src << 7) | etype
__global__ __launch_bounds__(256) void scatter_k(const int* __restrict__ dst,
                                                 const int* __restrict__ src,
                                                 const int* __restrict__ ef,
                                                 int* __restrict__ cursor,
                                                 int* __restrict__ csr){
  int e = blockIdx.x * 256 + threadIdx.x;
  if (e >= NE) return;
  int sv = src[e];
  int v = dst[e] * 4 + (sv >> SQSH);
  int pos = atomicAdd(&cursor[v], 1);
  csr[pos] = (sv << 7) | ef[e];
}

// ---------------- attn output: attn[e,h] = wl[type,h] * rdq[h>>1][dst][h&1]
__global__ __launch_bounds__(256) void attn_k(const int* __restrict__ dst,
                                              const int* __restrict__ ef,
                                              const float* __restrict__ rdq,
                                              const float* __restrict__ emb,
                                              float* __restrict__ attn){
  __shared__ float wl[40];
  int tid = threadIdx.x;
  if (tid < 40){
    int t = tid >> 3, h = tid & 7;
    float m = emb[h];
    for (int tt = 1; tt < NTY; ++tt) m = fmaxf(m, emb[tt * 8 + h]);
    wl[tid] = expf(emb[t * 8 + h] - m);
  }
  __syncthreads();
  int e = blockIdx.x * 256 + tid;
  if (e >= NE) return;
  int d = dst[e], t = ef[e];
  const float* wr = wl + t * 8;
  f32x4 o0, o1;
  #pragma unroll
  for (int q = 0; q < 4; q++){
    float2 rv = *(const float2*)(rdq + ((size_t)q * NND + d) * 2);
    float a = wr[2 * q] * rv.x, b = wr[2 * q + 1] * rv.y;
    if (q < 2){ o0[2 * q] = a; o0[2 * q + 1] = b; }
    else      { o1[2 * (q - 2)] = a; o1[2 * (q - 2) + 1] = b; }
  }
  __builtin_nontemporal_store(o0, (f32x4*)(attn + (size_t)e * 8));
  __builtin_nontemporal_store(o1, (f32x4*)(attn + (size_t)e * 8 + 4));
}

// ---------------- aggregation: rst = (Σ w·fsrc) / (Σ w), rd cancels.
// Round-2 request shape (8 lanes/node x 16B = ONE 128B line/edge-pass) +
// XCD-pinned pair-quarters (verified round 3/4). NEW: nodes visited in
// degree-sorted order (nperm) -> per-wave loop trip = max(deg of 8 nodes) ≈
// deg, killing the ~27% exec-mask divergence waste + equalizing block
// durations. cursor[v] (post-scatter) = bucket END; s = c.x - dg.x, e = c.w.
__device__ inline void acc8(uint4 v, float wt, f32x2* a){
  f32x2 w2; w2.x = wt; w2.y = wt;
  f32x2 t0; t0.x = __uint_as_float(v.x << 16); t0.y = __uint_as_float(v.x & 0xFFFF0000u);
  f32x2 t1; t1.x = __uint_as_float(v.y << 16); t1.y = __uint_as_float(v.y & 0xFFFF0000u);
  f32x2 t2; t2.x = __uint_as_float(v.z << 16); t2.y = __uint_as_float(v.z & 0xFFFF0000u);
  f32x2 t3; t3.x = __uint_as_float(v.w << 16); t3.y = __uint_as_float(v.w & 0xFFFF0000u);
  a[0] += w2 * t0; a[1] += w2 * t1; a[2] += w2 * t2; a[3] += w2 * t3;
}

#define NBLK ((NND + 31) / 32)            // 1563 node-blocks per quarter
#define NBH  ((NBLK + 1) / 2)             // 782 per (quarter, xcd-half)

__global__ __launch_bounds__(256) void agg_k(const u16* __restrict__ fsrc,
                                             const int* __restrict__ csr,
                                             const int* __restrict__ cursor,
                                             const int* __restrict__ deg4,
                                             const int* __restrict__ nperm,
                                             const float* __restrict__ emb,
                                             float* __restrict__ rst,
                                             float* __restrict__ rdq){
  __shared__ float wl[40];
  int tid = threadIdx.x;
  if (tid < 40){
    int t = tid >> 3, h = tid & 7;
    float m = emb[h];
    for (int tt = 1; tt < NTY; ++tt) m = fmaxf(m, emb[tt * 8 + h]);
    wl[tid] = expf(emb[t * 8 + h] - m);
  }
  __syncthreads();
  const int c  = blockIdx.x & 7;        // XCD (HW round-robin)
  const int q  = c >> 1;                // pair-quarter pinned to XCD pair
  const int nb = (blockIdx.x >> 3) * 2 + (c & 1);
  const int pidx = nb * 32 + (tid >> 3);
  if (pidx >= NND) return;
  const int node = nperm[pidx];
  const int sl = tid & 7;               // 8 lanes/node, 16B each = 128B line
  const int h  = 2 * q + (sl >> 2);     // head this lane accumulates
  const u16* qbase = fsrc + (size_t)q * (NND * 64) + sl * 8;
  const int v0 = node * 4;
  int4 c4 = *(const int4*)(cursor + v0);  // post-scatter: bucket END offsets
  int4 dg = *(const int4*)(deg4 + v0);
  int s = c4.x - dg.x;
  int e = c4.w;
  f32x2 a[4]; a[0] = 0.f; a[1] = 0.f; a[2] = 0.f; a[3] = 0.f;
  float ss = 0.f;
  int i = s;
  for (; i + 3 < e; i += 4){
    int p0 = csr[i], p1 = csr[i+1], p2 = csr[i+2], p3 = csr[i+3];
    uint4 v0g = *(const uint4*)(qbase + ((size_t)(p0 >> 7) << 6));
    uint4 v1g = *(const uint4*)(qbase + ((size_t)(p1 >> 7) << 6));
    uint4 v2g = *(const uint4*)(qbase + ((size_t)(p2 >> 7) << 6));
    uint4 v3g = *(const uint4*)(qbase + ((size_t)(p3 >> 7) << 6));
    float w0 = wl[(p0 & 7) * 8 + h];
    float w1 = wl[(p1 & 7) * 8 + h];
    float w2 = wl[(p2 & 7) * 8 + h];
    float w3 = wl[(p3 & 7) * 8 + h];
    acc8(v0g, w0, a); acc8(v1g, w1, a); acc8(v2g, w2, a); acc8(v3g, w3, a);
    ss += (w0 + w1) + (w2 + w3);
  }
  for (; i < e; i++){
    int p0 = csr[i];
    uint4 v0g = *(const uint4*)(qbase + ((size_t)(p0 >> 7) << 6));
    float w0 = wl[(p0 & 7) * 8 + h];
    acc8(v0g, w0, a);
    ss += w0;
  }
  float inv = 1.0f / (ss + 1e-12f);
  f32x4 o0, o1;
  o0[0] = a[0].x*inv; o0[1] = a[0].y*inv; o0[2] = a[1].x*inv; o0[3] = a[1].y*inv;
  o1[0] = a[2].x*inv; o1[1] = a[2].y*inv; o1[2] = a[3].x*inv; o1[3] = a[3].y*inv;
  float* orow = rst + (size_t)node * 256 + q * 64 + sl * 8;
  __builtin_nontemporal_store(o0, (f32x4*)orow);
  __builtin_nontemporal_store(o1, (f32x4*)(orow + 4));
  if ((sl & 3) == 0)
    __builtin_nontemporal_store(inv, rdq + ((size_t)q * NND + node) * 2 + (sl >> 2));
}

extern "C" void kernel_launch(void* const* d_in, const int* in_sizes, int n_in,
                              void* d_out, int out_size, void* d_ws, size_t ws_size,
                              hipStream_t stream) {
  const float* feat = (const float*)d_in[0];
  const float* fcw  = (const float*)d_in[1];
  const float* emb  = (const float*)d_in[2];
  const int*   ef   = (const int*)d_in[3];
  const int*   src  = (const int*)d_in[4];
  const int*   dst  = (const int*)d_in[5];

  float* rst  = (float*)d_out;                         // [50000, 8, 32]
  float* attn = (float*)d_out + (size_t)NND * NH * ND; // [800000, 8]

  char* ws = (char*)d_ws;
  size_t o = 0;
  u16* fsrc    = (u16*)(ws + o);   o += (size_t)NND * 256 * 2;   // 25.6 MB (pair-quarter-major)
  int* csr     = (int*)(ws + o);   o += (size_t)NE * 4;          // 3.2 MB
  int* offs4   = (int*)(ws + o);   o += (size_t)NV * 4 + 256;    // 800 KB
  int* deg4    = (int*)(ws + o);   o += (size_t)NV * 4 + 256;    // 800 KB
  int* cursor  = (int*)(ws + o);   o += (size_t)NV * 4 + 4096;   // 800 KB (+pad: prep covers 49*4096)
  float* rdq   = (float*)(ws + o); o += (size_t)NND * NH * 4;    // 1.6 MB [4][NND][2]
  int* degn    = (int*)(ws + o);   o += (size_t)NND * 4 + 1024;  // 200 KB
  int* nperm   = (int*)(ws + o);   o += (size_t)NND * 4 + 1024;  // 200 KB
  u16* wb      = (u16*)(ws + o);   o += (size_t)256 * 256 * 2;   // 128 KB
  int* bsum    = (int*)(ws + o);   o += 1024;                    // 256 ints
  int* bbase4  = (int*)(ws + o);   o += 1024;                    // 256 ints

  hipMemsetAsync(deg4, 0, (size_t)NV * 4, stream);

  wcvt_k<<<64, 256, 0, stream>>>(fcw, wb);
  gemm_k<<<391, 512, 0, stream>>>(feat, wb, fsrc, NND);
  count_k<<<(NE + 255) / 256, 256, 0, stream>>>(dst, src, deg4);
  scan1_k<<<(NV + 1023) / 1024, 256, 0, stream>>>(deg4, offs4, bsum, degn);
  scan2_k<<<1, 256, 0, stream>>>(bsum, bbase4, (NV + 1023) / 1024);
  prep_k<<<(NND + 1023) / 1024, 256, 0, stream>>>(degn, offs4, bbase4, cursor, nperm);
  scatter_k<<<(NE + 255) / 256, 256, 0, stream>>>(dst, src, ef, cursor, csr);
  agg_k<<<8 * NBH, 256, 0, stream>>>(fsrc, csr, cursor, deg4, nperm, emb, rst, rdq);
  attn_k<<<(NE + 255) / 256, 256, 0, stream>>>(dst, ef, rdq, emb, attn);
}

// Round 6
// 286.614 us; speedup vs baseline: 1.0447x; 1.0447x over previous
//
#include <hip/hip_runtime.h>

typedef unsigned short u16;
typedef unsigned int u32;
typedef __attribute__((ext_vector_type(8))) short bf16x8;
typedef __attribute__((ext_vector_type(4))) float f32x4;
typedef __attribute__((ext_vector_type(2))) float f32x2;

#define NND 50000
#define NE 800000
#define NH 8
#define ND 32
#define NTY 5
#define NV (NND * 4)              // virtual nodes: (node, src-quarter)
#define SQSH 14                   // src-quarter = src >> 14

__device__ inline u16 f2bf(float x){
  u32 u = __float_as_uint(x);
  return (u16)((u + 0x7FFFu + ((u >> 16) & 1u)) >> 16);
}

// ---------------- W pre-convert: fc_w fp32 -> bf16 once
__global__ __launch_bounds__(256) void wcvt_k(const float* __restrict__ W,
                                              u16* __restrict__ Wb){
  int i = (blockIdx.x * 256 + threadIdx.x) * 4;
  f32x4 v = __builtin_nontemporal_load((const f32x4*)(W + i));
  ushort4 h = make_ushort4(f2bf(v[0]), f2bf(v[1]), f2bf(v[2]), f2bf(v[3]));
  *(ushort4*)(Wb + i) = h;
}

// ---------------- GEMM: feat[M,256] @ fc_w[256,256]^T -> feat_src bf16, stored
// PAIR-QUARTER-MAJOR: fsrc[q][node][64] (q = col>>6) -> 128B rows so agg's
// gather is one full cache line per edge (request-rate floor; round-3 lesson).
__global__ __launch_bounds__(512, 4) void gemm_k(const float* __restrict__ A,
                                                 const u16* __restrict__ Wb,
                                                 u16* __restrict__ C, int M){
  __shared__ u16 As[128 * 64];  // 16KB: addr(r,ch) u16s = r*64 + ((ch^(r&7))*8)
  __shared__ u16 Ws[256 * 64];  // 32KB: addr(n,ch) u16s = n*64 + ((ch^(n&7))*8)
  const int tid  = threadIdx.x;
  const int m0   = blockIdx.x * 128;
  const int lane = tid & 63, wid = tid >> 6;
  const int wm = (wid >> 2) * 64, wn = (wid & 3) * 64;
  const int ml = lane & 15, quad = lane >> 4;

  f32x4 acc[4][4] = {};

  const int ra = tid >> 2, ca0 = (tid & 3) * 2;
  int rag = m0 + ra; if (rag >= M) rag = M - 1;   // clamp: garbage rows never stored
  const float* aRow = A + (size_t)rag * 256;
  const int rw = tid >> 1, hw = tid & 1;
  const u16* wRow = Wb + (size_t)rw * 256;

  for (int k0 = 0; k0 < 256; k0 += 64){
    #pragma unroll
    for (int q = 0; q < 2; q++){
      int ch = ca0 + q;
      f32x4 v0 = __builtin_nontemporal_load((const f32x4*)(aRow + k0 + ch * 8));
      f32x4 v1 = __builtin_nontemporal_load((const f32x4*)(aRow + k0 + ch * 8 + 4));
      ushort4 h0 = make_ushort4(f2bf(v0[0]), f2bf(v0[1]), f2bf(v0[2]), f2bf(v0[3]));
      ushort4 h1 = make_ushort4(f2bf(v1[0]), f2bf(v1[1]), f2bf(v1[2]), f2bf(v1[3]));
      u16* p = As + ra * 64 + ((ch ^ (ra & 7)) * 8);
      *(ushort4*)p = h0;
      *(ushort4*)(p + 4) = h1;
    }
    #pragma unroll
    for (int q = 0; q < 4; q++){
      int ch = hw * 4 + q;
      uint4 wv = *(const uint4*)(wRow + k0 + ch * 8);
      *(uint4*)(Ws + rw * 64 + ((ch ^ (rw & 7)) * 8)) = wv;
    }
    __syncthreads();
    #pragma unroll
    for (int kk = 0; kk < 64; kk += 32){
      bf16x8 af[4], wf[4];
      const int cA = (kk >> 3) + quad;
      #pragma unroll
      for (int t = 0; t < 4; t++){
        int r = wm + t * 16 + ml;
        af[t] = *(const bf16x8*)(As + r * 64 + ((cA ^ (r & 7)) * 8));
      }
      #pragma unroll
      for (int t = 0; t < 4; t++){
        int n = wn + t * 16 + ml;
        wf[t] = *(const bf16x8*)(Ws + n * 64 + ((cA ^ (n & 7)) * 8));
      }
      #pragma unroll
      for (int i = 0; i < 4; i++)
        #pragma unroll
        for (int j = 0; j < 4; j++)
          acc[i][j] = __builtin_amdgcn_mfma_f32_16x16x32_bf16(af[i], wf[j], acc[i][j], 0, 0, 0);
    }
    __syncthreads();
  }
  const size_t qoff = (size_t)(wn >> 6) * NND * 64;
  #pragma unroll
  for (int i = 0; i < 4; i++){
    #pragma unroll
    for (int rr = 0; rr < 4; rr++){
      int row = m0 + wm + i * 16 + quad * 4 + rr;
      if (row < M){
        u16* crow = C + qoff + (size_t)row * 64;
        #pragma unroll
        for (int j = 0; j < 4; j++)
          __builtin_nontemporal_store(f2bf(acc[i][j][rr]), crow + j * 16 + ml);
      }
    }
  }
}

// ---------------- count: per-(dst, src-quarter) degree only
__global__ __launch_bounds__(256) void count_k(const int* __restrict__ dst,
                                               const int* __restrict__ src,
                                               int* __restrict__ deg4){
  int e = blockIdx.x * 256 + threadIdx.x;
  if (e < NE)
    atomicAdd(&deg4[dst[e] * 4 + (src[e] >> SQSH)], 1);
}

// ---------------- scan NV=200k bucket degrees -> local offsets + block sums
__global__ __launch_bounds__(256) void scan1_k(const int* __restrict__ deg4,
                                               int* __restrict__ offs4,
                                               int* __restrict__ bsum){
  __shared__ int lds[256];
  int b = blockIdx.x, tid = threadIdx.x;
  int base = b * 1024 + tid * 4;
  int d[4]; int tsum = 0;
  #pragma unroll
  for (int j = 0; j < 4; j++){
    int v = (base + j < NV) ? deg4[base + j] : 0;
    d[j] = tsum; tsum += v;
  }
  lds[tid] = tsum; __syncthreads();
  for (int off = 1; off < 256; off <<= 1){
    int v = (tid >= off) ? lds[tid - off] : 0;
    __syncthreads();
    lds[tid] += v;
    __syncthreads();
  }
  int excl = lds[tid] - tsum;
  #pragma unroll
  for (int j = 0; j < 4; j++)
    if (base + j < NV) offs4[base + j] = excl + d[j];
  if (tid == 255) bsum[b] = lds[tid];
}

// 256-wide scan over up to 256 block sums (NV/1024 = 196 blocks)
__global__ __launch_bounds__(256) void scan2_k(const int* __restrict__ bsum,
                                               int* __restrict__ bbase, int nb){
  __shared__ int l[256];
  int tid = threadIdx.x;
  int v = (tid < nb) ? bsum[tid] : 0;
  l[tid] = v; __syncthreads();
  for (int off = 1; off < 256; off <<= 1){
    int u = (tid >= off) ? l[tid - off] : 0;
    __syncthreads();
    l[tid] += u;
    __syncthreads();
  }
  bbase[tid] = l[tid] - v;
}

// ---------------- prep: cursor[v] = absolute start offset (scatter's
// atomicAdd turns it into the bucket END offset, which agg consumes)
__global__ __launch_bounds__(256) void prep_k(const int* __restrict__ offs4,
                                              const int* __restrict__ bbase4,
                                              int* __restrict__ cursor){
  int v = blockIdx.x * 256 + threadIdx.x;
  if (v < NV) cursor[v] = offs4[v] + bbase4[v >> 10];
}

// ---------------- scatter edges into src-bucketed CSR via cursor atomics
// csr entry = (src << 7) | etype
__global__ __launch_bounds__(256) void scatter_k(const int* __restrict__ dst,
                                                 const int* __restrict__ src,
                                                 const int* __restrict__ ef,
                                                 int* __restrict__ cursor,
                                                 int* __restrict__ csr){
  int e = blockIdx.x * 256 + threadIdx.x;
  if (e >= NE) return;
  int sv = src[e];
  int v = dst[e] * 4 + (sv >> SQSH);
  int pos = atomicAdd(&cursor[v], 1);
  csr[pos] = (sv << 7) | ef[e];
}

// ---------------- attn output: attn[e,h] = wl[type,h] * rdq[h>>1][dst][h&1]
__global__ __launch_bounds__(256) void attn_k(const int* __restrict__ dst,
                                              const int* __restrict__ ef,
                                              const float* __restrict__ rdq,
                                              const float* __restrict__ emb,
                                              float* __restrict__ attn){
  __shared__ float wl[40];
  int tid = threadIdx.x;
  if (tid < 40){
    int t = tid >> 3, h = tid & 7;
    float m = emb[h];
    for (int tt = 1; tt < NTY; ++tt) m = fmaxf(m, emb[tt * 8 + h]);
    wl[tid] = expf(emb[t * 8 + h] - m);
  }
  __syncthreads();
  int e = blockIdx.x * 256 + tid;
  if (e >= NE) return;
  int d = dst[e], t = ef[e];
  const float* wr = wl + t * 8;
  f32x4 o0, o1;
  #pragma unroll
  for (int q = 0; q < 4; q++){
    float2 rv = *(const float2*)(rdq + ((size_t)q * NND + d) * 2);
    float a = wr[2 * q] * rv.x, b = wr[2 * q + 1] * rv.y;
    if (q < 2){ o0[2 * q] = a; o0[2 * q + 1] = b; }
    else      { o1[2 * (q - 2)] = a; o1[2 * (q - 2) + 1] = b; }
  }
  __builtin_nontemporal_store(o0, (f32x4*)(attn + (size_t)e * 8));
  __builtin_nontemporal_store(o1, (f32x4*)(attn + (size_t)e * 8 + 4));
}

// ---------------- aggregation: rst = (Σ w·fsrc) / (Σ w), rd cancels.
// Round-4 structure (8 lanes/node x 16B = ONE 128B line/edge; XCD-pinned
// pair-quarters, verified). NEW vs round 4: INTRA-BLOCK degree sort -- the
// block's 32 consecutive nodes are rank-sorted by degree in LDS, and waves
// take nodes in rank order. Same csr/rst/gather line sets as round 4 (the
// round-5 global permutation scattered side-structures and regressed); only
// the wave<->node assignment changes, so per-wave trip = max of 8 SIMILAR
// degrees (~-14% issue waste). Also: (s,e) loaded ONCE by 32 threads into
// LDS (round 4 loaded the same int4s on all 8 lanes).
__device__ inline void acc8(uint4 v, float wt, f32x2* a){
  f32x2 w2; w2.x = wt; w2.y = wt;
  f32x2 t0; t0.x = __uint_as_float(v.x << 16); t0.y = __uint_as_float(v.x & 0xFFFF0000u);
  f32x2 t1; t1.x = __uint_as_float(v.y << 16); t1.y = __uint_as_float(v.y & 0xFFFF0000u);
  f32x2 t2; t2.x = __uint_as_float(v.z << 16); t2.y = __uint_as_float(v.z & 0xFFFF0000u);
  f32x2 t3; t3.x = __uint_as_float(v.w << 16); t3.y = __uint_as_float(v.w & 0xFFFF0000u);
  a[0] += w2 * t0; a[1] += w2 * t1; a[2] += w2 * t2; a[3] += w2 * t3;
}

#define NBLK ((NND + 31) / 32)            // 1563 node-blocks per quarter
#define NBH  ((NBLK + 1) / 2)             // 782 per (quarter, xcd-half)

__global__ __launch_bounds__(256) void agg_k(const u16* __restrict__ fsrc,
                                             const int* __restrict__ csr,
                                             const int* __restrict__ cursor,
                                             const int* __restrict__ deg4,
                                             const float* __restrict__ emb,
                                             float* __restrict__ rst,
                                             float* __restrict__ rdq){
  __shared__ float wl[40];
  __shared__ int sdg[32];
  __shared__ int sse[32][2];
  __shared__ int sidx[32];
  int tid = threadIdx.x;
  if (tid < 40){
    int t = tid >> 3, h = tid & 7;
    float m = emb[h];
    for (int tt = 1; tt < NTY; ++tt) m = fmaxf(m, emb[tt * 8 + h]);
    wl[tid] = expf(emb[t * 8 + h] - m);
  }
  const int c  = blockIdx.x & 7;        // XCD (HW round-robin)
  const int q  = c >> 1;                // pair-quarter pinned to XCD pair
  const int nb = (blockIdx.x >> 3) * 2 + (c & 1);
  // 32 loader threads: fetch (s,e) once, publish degree for the rank sort
  if (tid < 32){
    int node = nb * 32 + tid;
    int s = 0, e = 0;
    if (node < NND){
      int v0 = node * 4;
      int4 c4 = *(const int4*)(cursor + v0);  // post-scatter: bucket ENDs
      int4 dg = *(const int4*)(deg4 + v0);
      s = c4.x - dg.x;
      e = c4.w;
    }
    sse[tid][0] = s; sse[tid][1] = e;
    sdg[tid] = e - s;
  }
  __syncthreads();
  if (tid < 32){
    int mydg = sdg[tid];
    int r = 0;
    #pragma unroll
    for (int j = 0; j < 32; j++){
      int dj = sdg[j];
      r += (dj > mydg) || (dj == mydg && j < tid);   // rank, degree-descending
    }
    sidx[r] = tid;
  }
  __syncthreads();
  const int gi = tid >> 3;              // group 0..31 takes rank gi
  const int li = sidx[gi];              // local node index
  const int node = nb * 32 + li;
  if (node >= NND) return;              // empty (s==e) anyway; no barriers below
  const int sl = tid & 7;               // 8 lanes/node, 16B each = 128B line
  const int h  = 2 * q + (sl >> 2);     // head this lane accumulates
  const u16* qbase = fsrc + (size_t)q * (NND * 64) + sl * 8;
  int s = sse[li][0];
  int e = sse[li][1];
  f32x2 a[4]; a[0] = 0.f; a[1] = 0.f; a[2] = 0.f; a[3] = 0.f;
  float ss = 0.f;
  int i = s;
  for (; i + 3 < e; i += 4){
    int p0 = csr[i], p1 = csr[i+1], p2 = csr[i+2], p3 = csr[i+3];
    uint4 v0g = *(const uint4*)(qbase + ((size_t)(p0 >> 7) << 6));
    uint4 v1g = *(const uint4*)(qbase + ((size_t)(p1 >> 7) << 6));
    uint4 v2g = *(const uint4*)(qbase + ((size_t)(p2 >> 7) << 6));
    uint4 v3g = *(const uint4*)(qbase + ((size_t)(p3 >> 7) << 6));
    float w0 = wl[(p0 & 7) * 8 + h];
    float w1 = wl[(p1 & 7) * 8 + h];
    float w2 = wl[(p2 & 7) * 8 + h];
    float w3 = wl[(p3 & 7) * 8 + h];
    acc8(v0g, w0, a); acc8(v1g, w1, a); acc8(v2g, w2, a); acc8(v3g, w3, a);
    ss += (w0 + w1) + (w2 + w3);
  }
  for (; i < e; i++){
    int p0 = csr[i];
    uint4 v0g = *(const uint4*)(qbase + ((size_t)(p0 >> 7) << 6));
    float w0 = wl[(p0 & 7) * 8 + h];
    acc8(v0g, w0, a);
    ss += w0;
  }
  float inv = 1.0f / (ss + 1e-12f);
  f32x4 o0, o1;
  o0[0] = a[0].x*inv; o0[1] = a[0].y*inv; o0[2] = a[1].x*inv; o0[3] = a[1].y*inv;
  o1[0] = a[2].x*inv; o1[1] = a[2].y*inv; o1[2] = a[3].x*inv; o1[3] = a[3].y*inv;
  float* orow = rst + (size_t)node * 256 + q * 64 + sl * 8;
  __builtin_nontemporal_store(o0, (f32x4*)orow);
  __builtin_nontemporal_store(o1, (f32x4*)(orow + 4));
  if ((sl & 3) == 0)
    __builtin_nontemporal_store(inv, rdq + ((size_t)q * NND + node) * 2 + (sl >> 2));
}

extern "C" void kernel_launch(void* const* d_in, const int* in_sizes, int n_in,
                              void* d_out, int out_size, void* d_ws, size_t ws_size,
                              hipStream_t stream) {
  const float* feat = (const float*)d_in[0];
  const float* fcw  = (const float*)d_in[1];
  const float* emb  = (const float*)d_in[2];
  const int*   ef   = (const int*)d_in[3];
  const int*   src  = (const int*)d_in[4];
  const int*   dst  = (const int*)d_in[5];

  float* rst  = (float*)d_out;                         // [50000, 8, 32]
  float* attn = (float*)d_out + (size_t)NND * NH * ND; // [800000, 8]

  char* ws = (char*)d_ws;
  size_t o = 0;
  u16* fsrc    = (u16*)(ws + o);   o += (size_t)NND * 256 * 2;   // 25.6 MB (pair-quarter-major)
  int* csr     = (int*)(ws + o);   o += (size_t)NE * 4;          // 3.2 MB
  int* offs4   = (int*)(ws + o);   o += (size_t)NV * 4 + 256;    // 800 KB
  int* deg4    = (int*)(ws + o);   o += (size_t)NV * 4 + 256;    // 800 KB
  int* cursor  = (int*)(ws + o);   o += (size_t)NV * 4 + 256;    // 800 KB
  float* rdq   = (float*)(ws + o); o += (size_t)NND * NH * 4;    // 1.6 MB [4][NND][2]
  u16* wb      = (u16*)(ws + o);   o += (size_t)256 * 256 * 2;   // 128 KB
  int* bsum    = (int*)(ws + o);   o += 1024;                    // 256 ints
  int* bbase4  = (int*)(ws + o);   o += 1024;                    // 256 ints

  hipMemsetAsync(deg4, 0, (size_t)NV * 4, stream);

  wcvt_k<<<64, 256, 0, stream>>>(fcw, wb);
  gemm_k<<<391, 512, 0, stream>>>(feat, wb, fsrc, NND);
  count_k<<<(NE + 255) / 256, 256, 0, stream>>>(dst, src, deg4);
  scan1_k<<<(NV + 1023) / 1024, 256, 0, stream>>>(deg4, offs4, bsum);
  scan2_k<<<1, 256, 0, stream>>>(bsum, bbase4, (NV + 1023) / 1024);
  prep_k<<<(NV + 255) / 256, 256, 0, stream>>>(offs4, bbase4, cursor);
  scatter_k<<<(NE + 255) / 256, 256, 0, stream>>>(dst, src, ef, cursor, csr);
  agg_k<<<8 * NBH, 256, 0, stream>>>(fsrc, csr, cursor, deg4, emb, rst, rdq);
  attn_k<<<(NE + 255) / 256, 256, 0, stream>>>(dst, ef, rdq, emb, attn);
}